// Round 1
// baseline (1628.420 us; speedup 1.0000x reference)
//
#include <hip/hip_runtime.h>

#define SEQ    512
#define PRED   336
#define NPTS   8
#define NG     8
#define NCOMP  18
#define BATCH  8192

// ---- kernel 1 (GEMM + argmax) config ----
#define RT     64      // batch rows per workgroup
#define CT     48      // cols per col-iteration (336 = 7*48)
#define NCI    7
#define KT     32      // k-tile (512 = 16*32)
#define NKT    16
#define TCD    12      // thread cols (16x12 = 192 threads)
#define BLK1   192
#define LROW   36      // padded LDS row stride in floats (KT+4, keeps 16B align)
#define XSLOTS 512     // 64 rows * 8 float4-chunks
#define NSLOT  896     // + 48 cols * 8 chunks
#define TAU    1e-3f
#define NEGBIG (-3.402823466e+38f)

__global__ __launch_bounds__(BLK1) void k1_gemm_argmax(
    const float* __restrict__ x, const float* __restrict__ Wp,
    const float* __restrict__ bp, int* __restrict__ pts,
    float* __restrict__ gaps)
{
  __shared__ float lds[2][(RT + CT) * LROW];
  __shared__ float lastv[RT];

  const int tid  = threadIdx.x;
  const int row0 = blockIdx.x * RT;
  const int g    = blockIdx.y;
  const int tr   = tid / TCD;
  const int tc   = tid - tr * TCD;

  if (tid < RT) lastv[tid] = x[(size_t)(row0 + tid) * SEQ + (SEQ - 1)];
  __syncthreads();

  // staging slot decode, hoisted out of all loops
  const float* gp[5];
  int   loff[5];
  float lsub[5];
  int   cstep[5];
  bool  valid[5];
#pragma unroll
  for (int i = 0; i < 5; ++i) {
    int s = tid + i * BLK1;
    valid[i] = (s < NSLOT);
    gp[i] = x; loff[i] = 0; lsub[i] = 0.f; cstep[i] = 0;
    if (s < XSLOTS) {                       // x slot
      int r = s >> 3, c = s & 7;
      gp[i]   = x + (size_t)(row0 + r) * SEQ + c * 4;
      loff[i] = r * LROW + c * 4;
      lsub[i] = lastv[r];
    } else if (s < NSLOT) {                 // W slot
      int s2 = s - XSLOTS;
      int cc = s2 >> 3, c = s2 & 7;
      gp[i]   = Wp + (size_t)(g * PRED + cc) * SEQ + c * 4;
      loff[i] = (RT + cc) * LROW + c * 4;
      cstep[i] = CT * SEQ;                  // advance 48 W-rows per col-iter
    }
  }

  float bv1[4], bv2[4];
  int   bi1[4];
#pragma unroll
  for (int i = 0; i < 4; ++i) { bv1[i] = NEGBIG; bv2[i] = NEGBIG; bi1[i] = 0; }

  for (int ci = 0; ci < NCI; ++ci) {
    float acc[4][4];
#pragma unroll
    for (int i = 0; i < 4; ++i)
#pragma unroll
      for (int j = 0; j < 4; ++j) acc[i][j] = 0.f;

    // prologue: stage kt=0 into buffer 0
    {
      float4 v[5];
#pragma unroll
      for (int i = 0; i < 5; ++i) if (valid[i]) v[i] = *(const float4*)(gp[i]);
#pragma unroll
      for (int i = 0; i < 5; ++i) if (valid[i]) {
        float4 t = v[i];
        t.x -= lsub[i]; t.y -= lsub[i]; t.z -= lsub[i]; t.w -= lsub[i];
        *(float4*)&lds[0][loff[i]] = t;
      }
    }
    __syncthreads();

    for (int kt = 0; kt < NKT; ++kt) {
      const int cur = kt & 1;
      float4 v[5];
      const bool dost = (kt + 1 < NKT);
      if (dost) {                           // issue next-tile loads early (T14)
#pragma unroll
        for (int i = 0; i < 5; ++i) if (valid[i])
          v[i] = *(const float4*)(gp[i] + (kt + 1) * KT);
      }
#pragma unroll
      for (int kk = 0; kk < KT; kk += 4) {
        float4 a4[4], b4[4];
#pragma unroll
        for (int i = 0; i < 4; ++i)
          a4[i] = *(const float4*)&lds[cur][(tr * 4 + i) * LROW + kk];
#pragma unroll
        for (int j = 0; j < 4; ++j)
          b4[j] = *(const float4*)&lds[cur][(RT + tc * 4 + j) * LROW + kk];
#pragma unroll
        for (int i = 0; i < 4; ++i)
#pragma unroll
          for (int j = 0; j < 4; ++j) {
            float s = acc[i][j];
            s = fmaf(a4[i].x, b4[j].x, s);
            s = fmaf(a4[i].y, b4[j].y, s);
            s = fmaf(a4[i].z, b4[j].z, s);
            s = fmaf(a4[i].w, b4[j].w, s);
            acc[i][j] = s;
          }
      }
      if (dost) {                           // write next tile late
#pragma unroll
        for (int i = 0; i < 5; ++i) if (valid[i]) {
          float4 t = v[i];
          t.x -= lsub[i]; t.y -= lsub[i]; t.z -= lsub[i]; t.w -= lsub[i];
          *(float4*)&lds[cur ^ 1][loff[i]] = t;
        }
      }
      __syncthreads();
    }

    // epilogue: add bias, update per-row top-2 (cols visited in increasing order)
#pragma unroll
    for (int j = 0; j < 4; ++j) {
      const int col = ci * CT + tc * 4 + j;
      const float bb = bp[g * PRED + col];
#pragma unroll
      for (int i = 0; i < 4; ++i) {
        const float vv = acc[i][j] + bb;
        if (vv > bv1[i]) { bv2[i] = bv1[i]; bv1[i] = vv; bi1[i] = col; }
        else              bv2[i] = fmaxf(bv2[i], vv);
      }
    }
#pragma unroll
    for (int i = 0; i < 5; ++i) if (valid[i]) gp[i] += cstep[i];
  }

  // cross-thread (12-way) top-2 reduction per row; reuse tile LDS
  float* red  = &lds[0][0];
  float* red2 = &lds[0][RT * TCD];
  int*   redi = (int*)&lds[1][0];
#pragma unroll
  for (int i = 0; i < 4; ++i) {
    const int r = tr * 4 + i;
    red [r * TCD + tc] = bv1[i];
    red2[r * TCD + tc] = bv2[i];
    redi[r * TCD + tc] = bi1[i];
  }
  __syncthreads();
  if (tid < RT) {
    float bv = NEGBIG, sv = NEGBIG; int bi = 0;
    for (int t = 0; t < TCD; ++t) {
      const float v  = red [tid * TCD + t];
      const float v2 = red2[tid * TCD + t];
      const int   ii = redi[tid * TCD + t];
      if (v > bv || (v == bv && ii < bi)) {
        sv = fmaxf(sv, bv); sv = fmaxf(sv, v2); bv = v; bi = ii;
      } else {
        sv = fmaxf(sv, v);
      }
    }
    pts [(size_t)(row0 + tid) * NPTS + g] = bi;
    gaps[(size_t)(row0 + tid) * NPTS + g] = bv - sv;   // >= 0
  }
}

// f64 re-argmax for groups whose f32 top-2 gap < TAU (expected ~hundreds)
__global__ __launch_bounds__(256) void k2_recheck(
    const float* __restrict__ x, const float* __restrict__ Wp,
    const float* __restrict__ bp, int* __restrict__ pts,
    const float* __restrict__ gaps)
{
  const int lane  = threadIdx.x & 63;
  const int wave  = (blockIdx.x * blockDim.x + threadIdx.x) >> 6;
  const int nwave = (gridDim.x * blockDim.x) >> 6;
  for (int idx = wave; idx < BATCH * NPTS; idx += nwave) {
    if (gaps[idx] >= TAU) continue;        // wave-uniform branch
    const int row = idx >> 3;
    const int g   = idx & 7;
    const double last = (double)x[(size_t)row * SEQ + (SEQ - 1)];
    double xc[8];
#pragma unroll
    for (int j = 0; j < 8; ++j)
      xc[j] = (double)x[(size_t)row * SEQ + lane * 8 + j] - last;
    double bv = -1e300; int bi = 0;
    for (int c = 0; c < PRED; ++c) {
      const float* w = Wp + (size_t)(g * PRED + c) * SEQ + lane * 8;
      double s = 0.0;
#pragma unroll
      for (int j = 0; j < 8; ++j) s += xc[j] * (double)w[j];
#pragma unroll
      for (int off = 32; off >= 1; off >>= 1) s += __shfl_xor(s, off);
      s += (double)bp[g * PRED + c];
      if (s > bv) { bv = s; bi = c; }      // identical across lanes
    }
    if (lane == 0) pts[idx] = bi;
  }
}

// sort + params + piecewise-linear assembly; one wave per batch row
__global__ __launch_bounds__(256) void k3_output(
    const float* __restrict__ x, const float* __restrict__ Wc,
    const float* __restrict__ bc, const int* __restrict__ pts,
    float* __restrict__ out)
{
  __shared__ float pshare[4][NCOMP + 2];
  const int lane = threadIdx.x & 63;
  const int wid  = threadIdx.x >> 6;
  const int row  = blockIdx.x * 4 + wid;
  const float* xr = x + (size_t)row * SEQ;
  const float last = xr[SEQ - 1];

  int p[8];
#pragma unroll
  for (int j = 0; j < 8; ++j) p[j] = pts[(size_t)row * NPTS + j];
  // Batcher odd-even merge sort, 19 comparators
#define CSW(a,b) { int lo_ = min(p[a], p[b]); int hi_ = max(p[a], p[b]); p[a] = lo_; p[b] = hi_; }
  CSW(0,1) CSW(2,3) CSW(4,5) CSW(6,7)
  CSW(0,2) CSW(1,3) CSW(4,6) CSW(5,7)
  CSW(1,2) CSW(5,6)
  CSW(0,4) CSW(1,5) CSW(2,6) CSW(3,7)
  CSW(2,4) CSW(3,5)
  CSW(1,2) CSW(3,4) CSW(5,6)
#undef CSW

  float xc[8];
  {
    float4 u0 = *(const float4*)(xr + lane * 8);
    float4 u1 = *(const float4*)(xr + lane * 8 + 4);
    xc[0] = u0.x - last; xc[1] = u0.y - last; xc[2] = u0.z - last; xc[3] = u0.w - last;
    xc[4] = u1.x - last; xc[5] = u1.y - last; xc[6] = u1.z - last; xc[7] = u1.w - last;
  }
  for (int s = 0; s < NCOMP; ++s) {
    const float* w = Wc + (size_t)s * SEQ + lane * 8;
    float4 w0 = *(const float4*)(w);
    float4 w1 = *(const float4*)(w + 4);
    float a = 0.f;
    a = fmaf(xc[0], w0.x, a); a = fmaf(xc[1], w0.y, a);
    a = fmaf(xc[2], w0.z, a); a = fmaf(xc[3], w0.w, a);
    a = fmaf(xc[4], w1.x, a); a = fmaf(xc[5], w1.y, a);
    a = fmaf(xc[6], w1.z, a); a = fmaf(xc[7], w1.w, a);
#pragma unroll
    for (int off = 32; off >= 1; off >>= 1) a += __shfl_xor(a, off);
    if (lane == 0) pshare[wid][s] = a + bc[s];
  }
  __syncthreads();
  for (int t = lane; t < PRED; t += 64) {
    int slot = 0;
#pragma unroll
    for (int j = 0; j < 8; ++j) slot += (p[j] <= t) ? 1 : 0;
    const float a = pshare[wid][slot * 2];
    const float b = pshare[wid][slot * 2 + 1];
    out[(size_t)row * PRED + t] = fmaf(a, (float)t, b) + last;
  }
}

extern "C" void kernel_launch(void* const* d_in, const int* in_sizes, int n_in,
                              void* d_out, int out_size, void* d_ws, size_t ws_size,
                              hipStream_t stream)
{
  const float* x  = (const float*)d_in[0];
  const float* Wp = (const float*)d_in[1];
  const float* bp = (const float*)d_in[2];
  const float* Wc = (const float*)d_in[3];
  const float* bc = (const float*)d_in[4];
  float* out  = (float*)d_out;
  int*   pts  = (int*)d_ws;                                   // 8192*8*4   = 256 KB
  float* gaps = (float*)((char*)d_ws + (size_t)BATCH * NPTS * 4); // + 256 KB

  hipLaunchKernelGGL(k1_gemm_argmax, dim3(BATCH / RT, NG), dim3(BLK1), 0, stream,
                     x, Wp, bp, pts, gaps);
  hipLaunchKernelGGL(k2_recheck, dim3(1024), dim3(256), 0, stream,
                     x, Wp, bp, pts, gaps);
  hipLaunchKernelGGL(k3_output, dim3(BATCH / 4), dim3(256), 0, stream,
                     x, Wc, bc, pts, out);
}

// Round 2
// 228.995 us; speedup vs baseline: 7.1112x; 7.1112x over previous
//
#include <hip/hip_runtime.h>

#define SEQ    512
#define PRED   336
#define NPTS   8
#define NG     8
#define NCOMP  18
#define BATCH  8192
#define TAU    3e-4f
#define NEGBIG (-3.402823466e+38f)

typedef __bf16 bf16x8 __attribute__((ext_vector_type(8)));
typedef float  f32x4  __attribute__((ext_vector_type(4)));

__device__ __forceinline__ void gload_lds16(const __bf16* g, __bf16* l) {
  __builtin_amdgcn_global_load_lds(
      (const __attribute__((address_space(1))) unsigned int*)(const void*)g,
      (__attribute__((address_space(3))) unsigned int*)(void*)l, 16, 0, 0);
}

// ---------------- k0: split f32 -> (hi,lo) bf16, interleaved [row][k/32][2][32]
__global__ __launch_bounds__(256) void k0_split(
    const float* __restrict__ src, __bf16* __restrict__ dst, int sublast)
{
  const int lane = threadIdx.x & 63, wid = threadIdx.x >> 6;
  const int row  = blockIdx.x * 4 + wid;
  const float* r = src + (size_t)row * SEQ;
  const float last = sublast ? r[SEQ - 1] : 0.f;
  float4 u0 = *(const float4*)&r[lane * 8];
  float4 u1 = *(const float4*)&r[lane * 8 + 4];
  float v[8] = {u0.x, u0.y, u0.z, u0.w, u1.x, u1.y, u1.z, u1.w};
  bf16x8 h, l;
#pragma unroll
  for (int j = 0; j < 8; ++j) {
    float xc = v[j] - last;              // f32 subtract, matches reference
    __bf16 hb = (__bf16)xc;              // RNE; xc - (float)hb is exact
    float rest = xc - (float)hb;
    h[j] = hb; l[j] = (__bf16)rest;
  }
  const int kb = lane >> 2, j0 = (lane & 3) * 8;
  const size_t base = (size_t)row * 1024 + kb * 64;
  *(bf16x8*)&dst[base + j0]      = h;
  *(bf16x8*)&dst[base + 32 + j0] = l;
}

// ---------------- k1: MFMA GEMM (3-term hi/lo) + per-tile top-2
// tile: BM=128 x BN=112, BK=32, 4 waves (stacked along M, 32 rows each)
// LDS layout (bf16 elems): A_hi[4][128][8] @0, A_lo @4096, B_hi[4][112][8] @8192, B_lo @11776
__global__ __launch_bounds__(256, 2) void k1_mfma(
    const __bf16* __restrict__ A, const __bf16* __restrict__ B,
    const float* __restrict__ bp,
    float* __restrict__ t1v, float* __restrict__ t2v, int* __restrict__ t1i)
{
  __shared__ __bf16 sbuf[2][15360];   // 2 x 30720 B = 60 KiB -> 2 blocks/CU
  const int tid  = threadIdx.x;
  const int lane = tid & 63, wid = tid >> 6;
  const int nt   = blockIdx.x;        // 0..23 (N-tile; 24 consecutive share A-tile)
  const int mt   = blockIdx.y;        // 0..63
  const int row0 = mt * 128;
  const int ncol0 = nt * 112;         // global W_pts row of tile col 0

  // 1920 16B-chunks per K-step; chunk c -> LDS byte c*16 (linear), slot i: c = i*256+tid
  const __bf16* gsrc[8];
  bool ok[8];
#pragma unroll
  for (int i = 0; i < 8; ++i) {
    const int c = i * 256 + tid;
    ok[i] = (c < 1920);               // wave-uniform (1920 = 30*64)
    const __bf16* p = A; size_t off = 0;
    if (c < 512)       { off = (size_t)(row0 + (c & 127)) * 1024 + ((c) >> 7) * 8; }
    else if (c < 1024) { int c2 = c - 512;
                         off = (size_t)(row0 + (c2 & 127)) * 1024 + 32 + (c2 >> 7) * 8; }
    else if (c < 1472) { int c2 = c - 1024; p = B;
                         off = (size_t)(ncol0 + c2 % 112) * 1024 + (c2 / 112) * 8; }
    else               { int c2 = c - 1472; p = B;
                         off = (size_t)(ncol0 + c2 % 112) * 1024 + 32 + (c2 / 112) * 8; }
    gsrc[i] = p + off;
  }
  const int ubase = ((tid >> 6) << 6) * 8;   // wave-uniform lds elem base (lane*16B added by HW)

  auto STAGE = [&](int kt, int b) {
#pragma unroll
    for (int i = 0; i < 8; ++i) if (ok[i])
      gload_lds16(gsrc[i] + kt * 64, &sbuf[b][i * 2048 + ubase]);
  };

  f32x4 acc[2][7];
#pragma unroll
  for (int m = 0; m < 2; ++m)
#pragma unroll
    for (int n = 0; n < 7; ++n) acc[m][n] = (f32x4){0.f, 0.f, 0.f, 0.f};

  const int lr = lane & 15, lk = lane >> 4;
  const int aidx = (lk * 128 + wid * 32 + lr) * 8;   // + m*128
  const int bidx = 8192 + (lk * 112 + lr) * 8;       // + n*128 ; lo at +3584

  STAGE(0, 0);
  __syncthreads();

#pragma unroll 2
  for (int kt = 0; kt < 16; ++kt) {
    const int cur = kt & 1;
    if (kt < 15) STAGE(kt + 1, cur ^ 1);
    const __bf16* sb = sbuf[cur];
    bf16x8 ah[2], al[2], bh[7], bl[7];
#pragma unroll
    for (int m = 0; m < 2; ++m) {
      ah[m] = *(const bf16x8*)&sb[aidx + m * 128];
      al[m] = *(const bf16x8*)&sb[4096 + aidx + m * 128];
    }
#pragma unroll
    for (int n = 0; n < 7; ++n) {
      bh[n] = *(const bf16x8*)&sb[bidx + n * 128];
      bl[n] = *(const bf16x8*)&sb[3584 + bidx + n * 128];
    }
#pragma unroll
    for (int n = 0; n < 7; ++n)
#pragma unroll
      for (int m = 0; m < 2; ++m) {
        acc[m][n] = __builtin_amdgcn_mfma_f32_16x16x32_bf16(ah[m], bh[n], acc[m][n], 0, 0, 0);
        acc[m][n] = __builtin_amdgcn_mfma_f32_16x16x32_bf16(ah[m], bl[n], acc[m][n], 0, 0, 0);
        acc[m][n] = __builtin_amdgcn_mfma_f32_16x16x32_bf16(al[m], bh[n], acc[m][n], 0, 0, 0);
      }
    __syncthreads();
  }

  // epilogue: bias + per-row top-2 over this tile's 112 cols
  const int g = nt / 3, colg0 = (nt % 3) * 112;
  float bias[7];
#pragma unroll
  for (int n = 0; n < 7; ++n) bias[n] = bp[g * PRED + colg0 + n * 16 + lr];
#pragma unroll
  for (int m = 0; m < 2; ++m)
#pragma unroll
    for (int r = 0; r < 4; ++r) {
      float v1 = NEGBIG, v2 = NEGBIG; int i1 = 0x7fffffff;
#pragma unroll
      for (int n = 0; n < 7; ++n) {
        const float v = acc[m][n][r] + bias[n];
        if (v > v1) { v2 = v1; v1 = v; i1 = colg0 + n * 16 + lr; }
        else         v2 = fmaxf(v2, v);
      }
#pragma unroll
      for (int d = 1; d < 16; d <<= 1) {      // reduce across lr (same-row lanes)
        const float o1 = __shfl_xor(v1, d), o2 = __shfl_xor(v2, d);
        const int   oi = __shfl_xor(i1, d);
        const bool  ow = (o1 > v1) || (o1 == v1 && oi < i1);
        v2 = fmaxf(ow ? v1 : o1, fmaxf(v2, o2));
        v1 = ow ? o1 : v1; i1 = ow ? oi : i1;
      }
      if (lr == 0) {
        const int rowg = row0 + wid * 32 + m * 16 + lk * 4 + r;
        const int o = rowg * 24 + nt;
        t1v[o] = v1; t2v[o] = v2; t1i[o] = i1;
      }
    }
}

// ---------------- k1b: merge 3 tiles/group -> pts + compacted recheck list
__global__ __launch_bounds__(256) void k1b_merge(
    const float* __restrict__ t1v, const float* __restrict__ t2v,
    const int* __restrict__ t1i, int* __restrict__ pts,
    int* __restrict__ list, int* __restrict__ counter)
{
  const int idx = blockIdx.x * 256 + threadIdx.x;   // 65536
  const int row = idx >> 3, g = idx & 7;
  float v1 = NEGBIG, v2 = NEGBIG; int i1 = 0x7fffffff;
#pragma unroll
  for (int t = 0; t < 3; ++t) {
    const int o = row * 24 + g * 3 + t;
    const float a1 = t1v[o], a2 = t2v[o]; const int ai = t1i[o];
    const bool w = (a1 > v1) || (a1 == v1 && ai < i1);
    v2 = fmaxf(w ? v1 : a1, fmaxf(v2, a2));
    if (w) { v1 = a1; i1 = ai; }
  }
  pts[idx] = i1;
  if (v1 - v2 < TAU) { const int p = atomicAdd(counter, 1); list[p] = idx; }
}

// ---------------- k2: f64 re-argmax, column-parallel (throughput-bound)
__global__ __launch_bounds__(256) void k2_recheck(
    const float* __restrict__ x, const float* __restrict__ Wp,
    const float* __restrict__ bp, int* __restrict__ pts,
    const int* __restrict__ list, const int* __restrict__ counter)
{
  __shared__ double xcs[4][SEQ];
  const int lane = threadIdx.x & 63, wid = threadIdx.x >> 6;
  const int n  = counter[0];
  const int wv = blockIdx.x * 4 + wid, nw = gridDim.x * 4;
  for (int ii = wv; ii < n; ii += nw) {
    const int idx = list[ii];
    const int row = idx >> 3, g = idx & 7;
    const float* xr = x + (size_t)row * SEQ;
    const float last = xr[SEQ - 1];
    {
      float4 u0 = *(const float4*)&xr[lane * 8];
      float4 u1 = *(const float4*)&xr[lane * 8 + 4];
      float vv[8] = {u0.x, u0.y, u0.z, u0.w, u1.x, u1.y, u1.z, u1.w};
#pragma unroll
      for (int j = 0; j < 8; ++j)
        xcs[wid][lane * 8 + j] = (double)(vv[j] - last);  // f32 sub, then promote
    }
    double bv = -1e300; int bi = 0x7fffffff;
    for (int c0 = 0; c0 < 384; c0 += 64) {
      const int col = c0 + lane;
      if (col < PRED) {
        const float* w = Wp + (size_t)(g * PRED + col) * SEQ;
        double s = (double)bp[g * PRED + col];
#pragma unroll 4
        for (int k = 0; k < SEQ; k += 4) {
          float4 wv = *(const float4*)&w[k];
          s += xcs[wid][k]     * (double)wv.x + xcs[wid][k + 1] * (double)wv.y
             + xcs[wid][k + 2] * (double)wv.z + xcs[wid][k + 3] * (double)wv.w;
        }
        if (s > bv || (s == bv && col < bi)) { bv = s; bi = col; }
      }
    }
#pragma unroll
    for (int d = 1; d < 64; d <<= 1) {
      const double o = __shfl_xor(bv, d); const int oi = __shfl_xor(bi, d);
      if (o > bv || (o == bv && oi < bi)) { bv = o; bi = oi; }
    }
    if (lane == 0) pts[idx] = bi;
  }
}

// ---------------- k3: sort + params + piecewise assembly (unchanged)
__global__ __launch_bounds__(256) void k3_output(
    const float* __restrict__ x, const float* __restrict__ Wc,
    const float* __restrict__ bc, const int* __restrict__ pts,
    float* __restrict__ out)
{
  __shared__ float pshare[4][NCOMP + 2];
  const int lane = threadIdx.x & 63;
  const int wid  = threadIdx.x >> 6;
  const int row  = blockIdx.x * 4 + wid;
  const float* xr = x + (size_t)row * SEQ;
  const float last = xr[SEQ - 1];

  int p[8];
#pragma unroll
  for (int j = 0; j < 8; ++j) p[j] = pts[(size_t)row * NPTS + j];
#define CSW(a,b) { int lo_ = min(p[a], p[b]); int hi_ = max(p[a], p[b]); p[a] = lo_; p[b] = hi_; }
  CSW(0,1) CSW(2,3) CSW(4,5) CSW(6,7)
  CSW(0,2) CSW(1,3) CSW(4,6) CSW(5,7)
  CSW(1,2) CSW(5,6)
  CSW(0,4) CSW(1,5) CSW(2,6) CSW(3,7)
  CSW(2,4) CSW(3,5)
  CSW(1,2) CSW(3,4) CSW(5,6)
#undef CSW

  float xc[8];
  {
    float4 u0 = *(const float4*)(xr + lane * 8);
    float4 u1 = *(const float4*)(xr + lane * 8 + 4);
    xc[0] = u0.x - last; xc[1] = u0.y - last; xc[2] = u0.z - last; xc[3] = u0.w - last;
    xc[4] = u1.x - last; xc[5] = u1.y - last; xc[6] = u1.z - last; xc[7] = u1.w - last;
  }
  for (int s = 0; s < NCOMP; ++s) {
    const float* w = Wc + (size_t)s * SEQ + lane * 8;
    float4 w0 = *(const float4*)(w);
    float4 w1 = *(const float4*)(w + 4);
    float a = 0.f;
    a = fmaf(xc[0], w0.x, a); a = fmaf(xc[1], w0.y, a);
    a = fmaf(xc[2], w0.z, a); a = fmaf(xc[3], w0.w, a);
    a = fmaf(xc[4], w1.x, a); a = fmaf(xc[5], w1.y, a);
    a = fmaf(xc[6], w1.z, a); a = fmaf(xc[7], w1.w, a);
#pragma unroll
    for (int off = 32; off >= 1; off >>= 1) a += __shfl_xor(a, off);
    if (lane == 0) pshare[wid][s] = a + bc[s];
  }
  __syncthreads();
  for (int t = lane; t < PRED; t += 64) {
    int slot = 0;
#pragma unroll
    for (int j = 0; j < 8; ++j) slot += (p[j] <= t) ? 1 : 0;
    const float a = pshare[wid][slot * 2];
    const float b = pshare[wid][slot * 2 + 1];
    out[(size_t)row * PRED + t] = fmaf(a, (float)t, b) + last;
  }
}

extern "C" void kernel_launch(void* const* d_in, const int* in_sizes, int n_in,
                              void* d_out, int out_size, void* d_ws, size_t ws_size,
                              hipStream_t stream)
{
  const float* x  = (const float*)d_in[0];
  const float* Wp = (const float*)d_in[1];
  const float* bp = (const float*)d_in[2];
  const float* Wc = (const float*)d_in[3];
  const float* bc = (const float*)d_in[4];
  float* out = (float*)d_out;

  // workspace layout (needs ~25.5 MB)
  char* w = (char*)d_ws;
  __bf16* Ahl = (__bf16*)w;                              w += (size_t)BATCH * 1024 * 2;      // 16 MB
  __bf16* Bhl = (__bf16*)w;                              w += (size_t)NG * PRED * 1024 * 2;  // 5.25 MB
  float* t1v  = (float*)w;                               w += (size_t)BATCH * 24 * 4;
  float* t2v  = (float*)w;                               w += (size_t)BATCH * 24 * 4;
  int*   t1i  = (int*)w;                                 w += (size_t)BATCH * 24 * 4;
  int*   pts  = (int*)w;                                 w += (size_t)BATCH * NPTS * 4;
  int*   list = (int*)w;                                 w += (size_t)BATCH * NPTS * 4;
  int*   counter = (int*)w;

  hipLaunchKernelGGL(k0_split, dim3(BATCH / 4), dim3(256), 0, stream, x,  Ahl, 1);
  hipLaunchKernelGGL(k0_split, dim3(NG * PRED / 4), dim3(256), 0, stream, Wp, Bhl, 0);
  hipLaunchKernelGGL(k1_mfma, dim3(24, 64), dim3(256), 0, stream,
                     Ahl, Bhl, bp, t1v, t2v, t1i);
  hipMemsetAsync(counter, 0, 4, stream);
  hipLaunchKernelGGL(k1b_merge, dim3(BATCH * NPTS / 256), dim3(256), 0, stream,
                     t1v, t2v, t1i, pts, list, counter);
  hipLaunchKernelGGL(k2_recheck, dim3(256), dim3(256), 0, stream,
                     x, Wp, bp, pts, list, counter);
  hipLaunchKernelGGL(k3_output, dim3(BATCH / 4), dim3(256), 0, stream,
                     x, Wc, bc, pts, out);
}